// Round 2
// baseline (1081.468 us; speedup 1.0000x reference)
//
#include <hip/hip_runtime.h>
#include <math.h>

// ---------------------------------------------------------------------------
// EqMotion fused implementation, fp32 VALU baseline.
// B=4, N=256, T_IN=10, T_OUT=20, HID=64, HALF=32, HC=64, NCAT=4.
// Outputs: x_out [4,256,20,3] (61440 f32) then category [4,256,256,4].
// Workspace layout (floats); total 983104 floats = 3.93 MB.
// ---------------------------------------------------------------------------

constexpr int WS_XC     = 0;                       // [4][3] stride 4
constexpr int WS_XMEAN  = 16;                      // [4][3] stride 4
constexpr int WS_XM2    = 32;                      // [4][3] stride 4
constexpr int WS_COORDT = 64;                      // [4][384][256]  (c*3+d major, n minor)
constexpr int WS_XH     = WS_COORDT + 4*384*256;   // [4][256][64][3]
constexpr int WS_HH     = WS_XH + 4*256*64*3;      // [4][256][64]
constexpr int WS_BIASE  = WS_HH + 4*256*64;        // [4][256][64]
constexpr int WS_CONTRE = WS_BIASE + 4*256*64;     // [4][64][256]  (transposed)
constexpr int WS_AGG    = WS_CONTRE + 4*256*64;    // [4][256][64]
constexpr int WS_BIASK  = WS_AGG + 4*256*64;       // [4][256][64]
constexpr int WS_CONTRK = WS_BIASK + 4*256*64;     // [4][64][256]

#define PI_F 3.14159265358979323846f
#define EPS_F 1e-6f

__device__ __forceinline__ float silu(float v) {
    float t = 1.0f + __expf(-v);
    return v * __builtin_amdgcn_rcpf(t);
}

// ---------------------------------------------------------------------------
// K0: per-batch stats.  S[t,d] = sum_n x[b,n,t,d]; x_center; x_mean (of DCT'd
// centered x, computed analytically: xmean_d = sum_t M_t*(S[t,d]/N - xc_d),
// M_t = mean_s dct[s,t]).
// ---------------------------------------------------------------------------
__global__ void k_stats(const float* __restrict__ x, float* __restrict__ ws) {
    int b = blockIdx.x;
    int tid = threadIdx.x, lane = tid & 63, w = tid >> 6;
    __shared__ float sred[4][30];
    float v[30];
    const float* xp = x + (b * 256 + tid) * 30;
#pragma unroll
    for (int t = 0; t < 30; ++t) v[t] = xp[t];
#pragma unroll
    for (int t = 0; t < 30; ++t) {
        float s = v[t];
#pragma unroll
        for (int m = 1; m < 64; m <<= 1) s += __shfl_xor(s, m, 64);
        if (lane == 0) sred[w][t] = s;
    }
    __syncthreads();
    if (tid == 0) {
        float S[30];
#pragma unroll
        for (int t = 0; t < 30; ++t) S[t] = sred[0][t] + sred[1][t] + sred[2][t] + sred[3][t];
        float xc[3];
        for (int d = 0; d < 3; ++d) {
            float s = 0.0f;
            for (int t = 0; t < 10; ++t) s += S[t * 3 + d];
            xc[d] = s * (1.0f / 2560.0f);
            ws[WS_XC + b * 4 + d] = xc[d];
        }
        float w0 = sqrtf(0.1f), w1 = sqrtf(0.2f);
        float xm[3] = {0.0f, 0.0f, 0.0f};
        for (int t = 0; t < 10; ++t) {
            float Mt = 0.0f;
            for (int s = 0; s < 10; ++s) {
                float wk = (s == 0) ? w0 : w1;
                Mt += wk * cosf(PI_F * (t + 0.5f) * s * 0.1f);
            }
            Mt *= 0.1f;
            for (int d = 0; d < 3; ++d) xm[d] += Mt * (S[t * 3 + d] * (1.0f / 256.0f) - xc[d]);
        }
        for (int d = 0; d < 3; ++d) ws[WS_XMEAN + b * 4 + d] = xm[d];
    }
}

// ---------------------------------------------------------------------------
// K1: per-node: DCT of x/vel, vel angles, hh embedding, xh/vh channels.
// 4 nodes per block (one wave each), lane = output channel (0..63).
// ---------------------------------------------------------------------------
__global__ void k_nodes(const float* __restrict__ x, const float* __restrict__ vel,
                        const float* __restrict__ h,
                        const float* __restrict__ W_emb, const float* __restrict__ b_emb,
                        const float* __restrict__ W_emb2, const float* __restrict__ b_emb2,
                        const float* __restrict__ W_coord, const float* __restrict__ W_vel,
                        float* __restrict__ ws) {
    int node = blockIdx.x * 4 + (threadIdx.x >> 6);
    int lane = threadIdx.x & 63;
    int b = node >> 8, n = node & 255;
    float xc[3], xm[3];
#pragma unroll
    for (int d = 0; d < 3; ++d) {
        xc[d] = ws[WS_XC + b * 4 + d];
        xm[d] = ws[WS_XMEAN + b * 4 + d];
    }
    const float* xp = x + node * 30;
    const float* vp = vel + node * 30;
    float xs[10][3], vl[10][3];
#pragma unroll
    for (int t = 0; t < 10; ++t)
#pragma unroll
        for (int d = 0; d < 3; ++d) {
            xs[t][d] = xp[t * 3 + d] - xc[d];
            vl[t][d] = vp[t * 3 + d];
        }
    // velocity angles (raw vel)
    float ang[10];
#pragma unroll
    for (int t = 0; t < 10; ++t) {
        int tp = (t == 0) ? 0 : (t - 1);
        float dot = 0.0f, n1 = 0.0f, n2 = 0.0f;
#pragma unroll
        for (int d = 0; d < 3; ++d) {
            float a = vl[tp][d], c = vl[t][d];
            dot += a * c; n1 += a * a; n2 += c * c;
        }
        float cv = dot / ((sqrtf(n1) + EPS_F) * (sqrtf(n2) + EPS_F));
        cv = fminf(1.0f, fmaxf(-1.0f, cv));
        ang[t] = acosf(cv);
    }
    // DCT (10x10), weights computed inline
    float xd[10][3], vd[10][3];
    float w0 = sqrtf(0.1f), w1 = sqrtf(0.2f);
#pragma unroll
    for (int s = 0; s < 10; ++s) {
        float a0 = 0, a1 = 0, a2 = 0, c0 = 0, c1 = 0, c2 = 0;
#pragma unroll
        for (int t = 0; t < 10; ++t) {
            float coef = ((s == 0) ? w0 : w1) * cosf(PI_F * (t + 0.5f) * s * 0.1f);
            a0 += coef * xs[t][0]; a1 += coef * xs[t][1]; a2 += coef * xs[t][2];
            c0 += coef * vl[t][0]; c1 += coef * vl[t][1]; c2 += coef * vl[t][2];
        }
        xd[s][0] = a0; xd[s][1] = a1; xd[s][2] = a2;
        vd[s][0] = c0; vd[s][1] = c1; vd[s][2] = c2;
    }
    // hh = cat(h @ W_emb + b_emb, ang @ W_emb2 + b_emb2)
    const float* hp = h + node * 10;
    float acc;
    if (lane < 32) {
        acc = b_emb[lane];
#pragma unroll
        for (int t = 0; t < 10; ++t) acc += hp[t] * W_emb[t * 32 + lane];
    } else {
        int o2 = lane - 32;
        acc = b_emb2[o2];
#pragma unroll
        for (int t = 0; t < 10; ++t) acc += ang[t] * W_emb2[t * 32 + o2];
    }
    ws[WS_HH + node * 64 + lane] = acc;
    // xh (c = lane) and vh
    float xh[3] = {xm[0], xm[1], xm[2]};
    float vh[3] = {0.0f, 0.0f, 0.0f};
#pragma unroll
    for (int t = 0; t < 10; ++t) {
        float wc = W_coord[t * 64 + lane];
        float wv = W_vel[t * 64 + lane];
#pragma unroll
        for (int d = 0; d < 3; ++d) {
            xh[d] += (xd[t][d] - xm[d]) * wc;
            vh[d] += vd[t][d] * wv;
        }
    }
    int cb = b * 384 * 256;
#pragma unroll
    for (int d = 0; d < 3; ++d) {
        ws[WS_XH + (node * 64 + lane) * 3 + d] = xh[d];
        ws[WS_COORDT + cb + (lane * 3 + d) * 256 + n] = xh[d];
        ws[WS_COORDT + cb + ((64 + lane) * 3 + d) * 256 + n] = vh[d];
    }
}

// ---------------------------------------------------------------------------
// K2: xm2 = mean over (n,c) of xh.
// ---------------------------------------------------------------------------
__global__ void k_xm2(float* __restrict__ ws) {
    int b = blockIdx.x, tid = threadIdx.x, lane = tid & 63, w = tid >> 6;
    const float* p = ws + WS_XH + (b * 256 + tid) * 192;
    float s0 = 0, s1 = 0, s2 = 0;
    for (int c = 0; c < 64; ++c) {
        s0 += p[c * 3 + 0]; s1 += p[c * 3 + 1]; s2 += p[c * 3 + 2];
    }
#pragma unroll
    for (int m = 1; m < 64; m <<= 1) {
        s0 += __shfl_xor(s0, m, 64);
        s1 += __shfl_xor(s1, m, 64);
        s2 += __shfl_xor(s2, m, 64);
    }
    __shared__ float sr[4][3];
    if (lane == 0) { sr[w][0] = s0; sr[w][1] = s1; sr[w][2] = s2; }
    __syncthreads();
    if (tid == 0)
        for (int d = 0; d < 3; ++d)
            ws[WS_XM2 + b * 4 + d] = (sr[0][d] + sr[1][d] + sr[2][d] + sr[3][d]) * (1.0f / 16384.0f);
}

// ---------------------------------------------------------------------------
// K3: prediction head + inverse DCT -> d_out[0 : 61440].
// IDCT = dct20^T (orthonormal DCT-II).
// ---------------------------------------------------------------------------
__global__ void k_xout(const float* __restrict__ W_pred, const float* __restrict__ ws,
                       float* __restrict__ out) {
    int nd = threadIdx.x >> 6, lane = threadIdx.x & 63;
    int node = blockIdx.x * 4 + nd;
    int b = node >> 8;
    __shared__ float sxp[4][60];
    float xm2[3];
#pragma unroll
    for (int d = 0; d < 3; ++d) xm2[d] = ws[WS_XM2 + b * 4 + d];
    if (lane < 60) {
        int o2 = lane / 3, d = lane % 3;
        const float* p = ws + WS_XH + node * 192;
        float acc = xm2[d];
        for (int c = 0; c < 64; ++c) acc += (p[c * 3 + d] - xm2[d]) * W_pred[c * 20 + o2];
        sxp[nd][lane] = acc;
    }
    __syncthreads();
    if (lane < 60) {
        int s = lane / 3, d = lane % 3;
        float w0 = sqrtf(0.05f), w1 = sqrtf(0.1f);
        float acc = ws[WS_XC + b * 4 + d];
#pragma unroll
        for (int t = 0; t < 20; ++t) {
            float coef = ((t == 0) ? w0 : w1) * cosf(PI_F * (s + 0.5f) * t * 0.05f);
            acc += coef * sxp[nd][t * 3 + d];
        }
        out[(node * 20 + s) * 3 + d] = acc;
    }
}

// ---------------------------------------------------------------------------
// K4: per-node edge-MLP rank-1 terms:
//   bias_e[n,o]   = be1[o] + sum_t hh[n,t]*We1[t, o]        (h1 slot)
//   contribT[o,n] =          sum_t hh[n,t]*We1[64+t, o]     (h2 slot)
// ---------------------------------------------------------------------------
__global__ void k_contrib1(const float* __restrict__ We1, const float* __restrict__ be1,
                           float* __restrict__ ws) {
    int node = blockIdx.x * 4 + (threadIdx.x >> 6);
    int o = threadIdx.x & 63;
    int b = node >> 8, n = node & 255;
    const float* hp = ws + WS_HH + node * 64;
    float a1 = be1[o], a2 = 0.0f;
    for (int t = 0; t < 64; ++t) {
        float hv = hp[t];
        a1 = fmaf(hv, We1[t * 64 + o], a1);
        a2 = fmaf(hv, We1[(64 + t) * 64 + o], a2);
    }
    ws[WS_BIASE + node * 64 + o] = a1;
    ws[WS_CONTRE + (b * 64 + o) * 256 + n] = a2;
}

// ---------------------------------------------------------------------------
// K5: pass A — dense pairs: dist -> coord_dist MLP -> edge MLP -> agg[b,i,:].
// block = (b,i); thread j = one pair.
// ---------------------------------------------------------------------------
__global__ __launch_bounds__(256) void k_passA(
    const float* __restrict__ Wc1, const float* __restrict__ bc1,
    const float* __restrict__ Wc2, const float* __restrict__ bc2,
    const float* __restrict__ We1,
    const float* __restrict__ We2, const float* __restrict__ be2,
    float* __restrict__ ws) {
    int i = blockIdx.x, b = blockIdx.y;
    int j = threadIdx.x, lane = j & 63, w = j >> 6;
    __shared__ float sci[384];
    __shared__ float sbias[64];
    __shared__ float sred[4][64];
    const float* cT = ws + WS_COORDT + b * 384 * 256;
    for (int idx = j; idx < 384; idx += 256) sci[idx] = cT[idx * 256 + i];
    if (j < 64) sbias[j] = ws[WS_BIASE + (b * 256 + i) * 64 + j];
    __syncthreads();

    const float* cTj = cT + j;
    // layer 1: t1 = dist @ Wc1 + bc1
    float t1[64];
#pragma unroll
    for (int o = 0; o < 64; ++o) t1[o] = bc1[o];
    for (int c = 0; c < 128; ++c) {
        float dx = sci[c * 3 + 0] - cTj[(c * 3 + 0) * 256];
        float dy = sci[c * 3 + 1] - cTj[(c * 3 + 1) * 256];
        float dz = sci[c * 3 + 2] - cTj[(c * 3 + 2) * 256];
        float dist = sqrtf(dx * dx + dy * dy + dz * dz);
        const float* wr = Wc1 + c * 64;
#pragma unroll
        for (int o = 0; o < 64; ++o) t1[o] = fmaf(dist, wr[o], t1[o]);
    }
#pragma unroll
    for (int o = 0; o < 64; ++o) t1[o] = silu(t1[o]);

    // e1 accumulator starts from rank-1 hh terms
    float e1[64];
    {
        const float* ce = ws + WS_CONTRE + b * 64 * 256 + j;
#pragma unroll
        for (int o = 0; o < 64; ++o) e1[o] = sbias[o] + ce[o * 256];
    }
    // coord_dist in chunks of 32, consumed immediately into e1
#pragma unroll 1
    for (int q = 0; q < 4; ++q) {
        float cd[32];
#pragma unroll
        for (int m = 0; m < 32; ++m) cd[m] = bc2[q * 32 + m];
        for (int o = 0; o < 64; ++o) {
            float v = t1[o];
            const float* wr = Wc2 + o * 128 + q * 32;
#pragma unroll
            for (int m = 0; m < 32; ++m) cd[m] = fmaf(v, wr[m], cd[m]);
        }
#pragma unroll
        for (int m = 0; m < 32; ++m) cd[m] = silu(cd[m]);
        for (int m = 0; m < 32; ++m) {
            float v = cd[m];
            const float* wr = We1 + (128 + q * 32 + m) * 64;
#pragma unroll
            for (int o = 0; o < 64; ++o) e1[o] = fmaf(v, wr[o], e1[o]);
        }
    }
#pragma unroll
    for (int o = 0; o < 64; ++o) e1[o] = silu(e1[o]);

    // edge = silu(e1 @ We2 + be2), masked at j==i
    float mfac = (j == i) ? 0.0f : 1.0f;
    float edge[64];
#pragma unroll
    for (int m = 0; m < 64; ++m) edge[m] = be2[m];
    for (int o = 0; o < 64; ++o) {
        float v = e1[o];
        const float* wr = We2 + o * 64;
#pragma unroll
        for (int m = 0; m < 64; ++m) edge[m] = fmaf(v, wr[m], edge[m]);
    }
#pragma unroll
    for (int m = 0; m < 64; ++m) edge[m] = mfac * silu(edge[m]);

    // butterfly array-reduce: lane ends with sum over wave of channel bitrev6(lane)
#pragma unroll
    for (int k = 0; k < 6; ++k) {
        int mk = 1 << k;
        int half = 32 >> k;
        bool up = (lane & mk) != 0;
#pragma unroll
        for (int t = 0; t < half; ++t) {
            float a = edge[t], bb = edge[t + half];
            float mine = up ? bb : a;
            float send = up ? a : bb;
            float recv = __shfl_xor(send, mk, 64);
            edge[t] = mine + recv;
        }
    }
    int c = ((lane & 1) << 5) | ((lane & 2) << 3) | ((lane & 4) << 1) |
            ((lane & 8) >> 1) | ((lane & 16) >> 3) | ((lane & 32) >> 5);
    sred[w][c] = edge[0];
    __syncthreads();
    if (j < 64)
        ws[WS_AGG + (b * 256 + i) * 64 + j] = sred[0][j] + sred[1][j] + sred[2][j] + sred[3][j];
}

// ---------------------------------------------------------------------------
// K6: node_new MLP + category-head rank-1 terms (bias_k, contrib_kT).
// ---------------------------------------------------------------------------
__global__ void k_nodes2(const float* __restrict__ Wn1, const float* __restrict__ bn1,
                         const float* __restrict__ Wn2, const float* __restrict__ bn2,
                         const float* __restrict__ Wk1, const float* __restrict__ bk1,
                         float* __restrict__ ws) {
    int nd = threadIdx.x >> 6;
    int o = threadIdx.x & 63;
    int node = blockIdx.x * 4 + nd;
    int b = node >> 8, n = node & 255;
    __shared__ float sg[4][64], snn[4][64];
    const float* hp = ws + WS_HH + node * 64;
    const float* ap = ws + WS_AGG + node * 64;
    float acc = bn1[o];
    for (int t = 0; t < 64; ++t) acc = fmaf(hp[t], Wn1[t * 64 + o], acc);
    for (int t = 0; t < 64; ++t) acc = fmaf(ap[t], Wn1[(64 + t) * 64 + o], acc);
    sg[nd][o] = silu(acc);
    __syncthreads();
    acc = bn2[o];
    for (int t = 0; t < 64; ++t) acc = fmaf(sg[nd][t], Wn2[t * 64 + o], acc);
    snn[nd][o] = silu(acc);
    __syncthreads();
    float bk = bk1[o], ck = 0.0f;
    for (int t = 0; t < 64; ++t) {
        float v = snn[nd][t];
        bk = fmaf(v, Wk1[t * 64 + o], bk);
        ck = fmaf(v, Wk1[(64 + t) * 64 + o], ck);
    }
    ws[WS_BIASK + node * 64 + o] = bk;
    ws[WS_CONTRK + (b * 64 + o) * 256 + n] = ck;
}

// ---------------------------------------------------------------------------
// K7: pass B — recompute dist/coord_dist, category logits (WITH final SiLU,
// per _mlp2) + softmax -> d_out[61440 + ...].
// ---------------------------------------------------------------------------
__global__ __launch_bounds__(256) void k_passB(
    const float* __restrict__ Wc1, const float* __restrict__ bc1,
    const float* __restrict__ Wc2, const float* __restrict__ bc2,
    const float* __restrict__ Wk1,
    const float* __restrict__ Wk2, const float* __restrict__ bk2,
    const float* __restrict__ ws, float* __restrict__ out) {
    int i = blockIdx.x, b = blockIdx.y;
    int j = threadIdx.x;
    __shared__ float sci[384];
    __shared__ float sbias[64];
    const float* cT = ws + WS_COORDT + b * 384 * 256;
    for (int idx = j; idx < 384; idx += 256) sci[idx] = cT[idx * 256 + i];
    if (j < 64) sbias[j] = ws[WS_BIASK + (b * 256 + i) * 64 + j];
    __syncthreads();

    const float* cTj = cT + j;
    float t1[64];
#pragma unroll
    for (int o = 0; o < 64; ++o) t1[o] = bc1[o];
    for (int c = 0; c < 128; ++c) {
        float dx = sci[c * 3 + 0] - cTj[(c * 3 + 0) * 256];
        float dy = sci[c * 3 + 1] - cTj[(c * 3 + 1) * 256];
        float dz = sci[c * 3 + 2] - cTj[(c * 3 + 2) * 256];
        float dist = sqrtf(dx * dx + dy * dy + dz * dz);
        const float* wr = Wc1 + c * 64;
#pragma unroll
        for (int o = 0; o < 64; ++o) t1[o] = fmaf(dist, wr[o], t1[o]);
    }
#pragma unroll
    for (int o = 0; o < 64; ++o) t1[o] = silu(t1[o]);

    float l1[64];
    {
        const float* ck = ws + WS_CONTRK + b * 64 * 256 + j;
#pragma unroll
        for (int o = 0; o < 64; ++o) l1[o] = sbias[o] + ck[o * 256];
    }
#pragma unroll 1
    for (int q = 0; q < 4; ++q) {
        float cd[32];
#pragma unroll
        for (int m = 0; m < 32; ++m) cd[m] = bc2[q * 32 + m];
        for (int o = 0; o < 64; ++o) {
            float v = t1[o];
            const float* wr = Wc2 + o * 128 + q * 32;
#pragma unroll
            for (int m = 0; m < 32; ++m) cd[m] = fmaf(v, wr[m], cd[m]);
        }
#pragma unroll
        for (int m = 0; m < 32; ++m) cd[m] = silu(cd[m]);
        for (int m = 0; m < 32; ++m) {
            float v = cd[m];
            const float* wr = Wk1 + (128 + q * 32 + m) * 64;
#pragma unroll
            for (int o = 0; o < 64; ++o) l1[o] = fmaf(v, wr[o], l1[o]);
        }
    }
#pragma unroll
    for (int o = 0; o < 64; ++o) l1[o] = silu(l1[o]);

    float lg[4] = {bk2[0], bk2[1], bk2[2], bk2[3]};
    for (int o = 0; o < 64; ++o) {
        float v = l1[o];
        const float* wr = Wk2 + o * 4;
#pragma unroll
        for (int k = 0; k < 4; ++k) lg[k] = fmaf(v, wr[k], lg[k]);
    }
    // _mlp2 applies SiLU after the second Linear too -> logits = silu(.)
#pragma unroll
    for (int k = 0; k < 4; ++k) lg[k] = silu(lg[k]);
    float mx = fmaxf(fmaxf(lg[0], lg[1]), fmaxf(lg[2], lg[3]));
    float e0 = __expf(lg[0] - mx), e1v = __expf(lg[1] - mx);
    float e2 = __expf(lg[2] - mx), e3 = __expf(lg[3] - mx);
    float inv = __builtin_amdgcn_rcpf(e0 + e1v + e2 + e3);
    float4 r = make_float4(e0 * inv, e1v * inv, e2 * inv, e3 * inv);
    reinterpret_cast<float4*>(out + 61440)[(b * 256 + i) * 256 + j] = r;
}

// ---------------------------------------------------------------------------
extern "C" void kernel_launch(void* const* d_in, const int* in_sizes, int n_in,
                              void* d_out, int out_size, void* d_ws, size_t ws_size,
                              hipStream_t stream) {
    (void)in_sizes; (void)n_in; (void)out_size; (void)ws_size;
    const float* h      = (const float*)d_in[0];
    const float* x      = (const float*)d_in[1];
    const float* vel    = (const float*)d_in[2];
    const float* W_emb  = (const float*)d_in[3];
    const float* b_emb  = (const float*)d_in[4];
    const float* W_emb2 = (const float*)d_in[5];
    const float* b_emb2 = (const float*)d_in[6];
    const float* W_coord= (const float*)d_in[7];
    const float* W_vel  = (const float*)d_in[8];
    const float* W_pred = (const float*)d_in[9];
    const float* Wc1    = (const float*)d_in[10];
    const float* bc1    = (const float*)d_in[11];
    const float* Wc2    = (const float*)d_in[12];
    const float* bc2    = (const float*)d_in[13];
    const float* We1    = (const float*)d_in[14];
    const float* be1    = (const float*)d_in[15];
    const float* We2    = (const float*)d_in[16];
    const float* be2    = (const float*)d_in[17];
    const float* Wn1    = (const float*)d_in[18];
    const float* bn1    = (const float*)d_in[19];
    const float* Wn2    = (const float*)d_in[20];
    const float* bn2    = (const float*)d_in[21];
    const float* Wk1    = (const float*)d_in[22];
    const float* bk1    = (const float*)d_in[23];
    const float* Wk2    = (const float*)d_in[24];
    const float* bk2    = (const float*)d_in[25];
    float* ws  = (float*)d_ws;
    float* out = (float*)d_out;

    k_stats<<<4, 256, 0, stream>>>(x, ws);
    k_nodes<<<256, 256, 0, stream>>>(x, vel, h, W_emb, b_emb, W_emb2, b_emb2,
                                     W_coord, W_vel, ws);
    k_xm2<<<4, 256, 0, stream>>>(ws);
    k_xout<<<256, 256, 0, stream>>>(W_pred, ws, out);
    k_contrib1<<<256, 256, 0, stream>>>(We1, be1, ws);
    k_passA<<<dim3(256, 4), 256, 0, stream>>>(Wc1, bc1, Wc2, bc2, We1, We2, be2, ws);
    k_nodes2<<<256, 256, 0, stream>>>(Wn1, bn1, Wn2, bn2, Wk1, bk1, ws);
    k_passB<<<dim3(256, 4), 256, 0, stream>>>(Wc1, bc1, Wc2, bc2, Wk1, Wk2, bk2, ws, out);
}

// Round 4
// 246.052 us; speedup vs baseline: 4.3953x; 4.3953x over previous
//
#include <hip/hip_runtime.h>
#include <math.h>

// ---------------------------------------------------------------------------
// EqMotion fused implementation. Pair passes on MFMA (fp16), rest fp32 VALU.
// B=4, N=256, T_IN=10, T_OUT=20, HID=64, HALF=32, HC=64, NCAT=4.
// Outputs: x_out [4,256,20,3] (61440 f32) then category [4,256,256,4].
// ---------------------------------------------------------------------------

constexpr int WS_XC     = 0;                       // [4][3] stride 4
constexpr int WS_XMEAN  = 16;                      // [4][3] stride 4
constexpr int WS_XM2    = 32;                      // [4][3] stride 4
constexpr int WS_COORDT = 64;                      // [4][384][256]  (c*3+d major, n minor)
constexpr int WS_XH     = WS_COORDT + 4*384*256;   // [4][256][64][3]
constexpr int WS_HH     = WS_XH + 4*256*64*3;      // [4][256][64]
constexpr int WS_BIASE  = WS_HH + 4*256*64;        // [4][256][64]
constexpr int WS_CONTRE = WS_BIASE + 4*256*64;     // [4][64][256]  (transposed)
constexpr int WS_AGG    = WS_CONTRE + 4*256*64;    // [4][256][64]
constexpr int WS_BIASK  = WS_AGG + 4*256*64;       // [4][256][64]
constexpr int WS_CONTRK = WS_BIASK + 4*256*64;     // [4][64][256]

#define PI_F 3.14159265358979323846f
#define EPS_F 1e-6f

typedef _Float16 f16x8 __attribute__((ext_vector_type(8)));
typedef float f32x4 __attribute__((ext_vector_type(4)));

__device__ __forceinline__ float silu(float v) {
    float t = 1.0f + __expf(-v);
    return v * __builtin_amdgcn_rcpf(t);
}

// ---------------------------------------------------------------------------
// K0: per-batch stats (x_center, x_mean of DCT'd centered x).
// ---------------------------------------------------------------------------
__global__ void k_stats(const float* __restrict__ x, float* __restrict__ ws) {
    int b = blockIdx.x;
    int tid = threadIdx.x, lane = tid & 63, w = tid >> 6;
    __shared__ float sred[4][30];
    float v[30];
    const float* xp = x + (b * 256 + tid) * 30;
#pragma unroll
    for (int t = 0; t < 30; ++t) v[t] = xp[t];
#pragma unroll
    for (int t = 0; t < 30; ++t) {
        float s = v[t];
#pragma unroll
        for (int m = 1; m < 64; m <<= 1) s += __shfl_xor(s, m, 64);
        if (lane == 0) sred[w][t] = s;
    }
    __syncthreads();
    if (tid == 0) {
        float S[30];
#pragma unroll
        for (int t = 0; t < 30; ++t) S[t] = sred[0][t] + sred[1][t] + sred[2][t] + sred[3][t];
        float xc[3];
        for (int d = 0; d < 3; ++d) {
            float s = 0.0f;
            for (int t = 0; t < 10; ++t) s += S[t * 3 + d];
            xc[d] = s * (1.0f / 2560.0f);
            ws[WS_XC + b * 4 + d] = xc[d];
        }
        float w0 = sqrtf(0.1f), w1 = sqrtf(0.2f);
        float xm[3] = {0.0f, 0.0f, 0.0f};
        for (int t = 0; t < 10; ++t) {
            float Mt = 0.0f;
            for (int s = 0; s < 10; ++s) {
                float wk = (s == 0) ? w0 : w1;
                Mt += wk * cosf(PI_F * (t + 0.5f) * s * 0.1f);
            }
            Mt *= 0.1f;
            for (int d = 0; d < 3; ++d) xm[d] += Mt * (S[t * 3 + d] * (1.0f / 256.0f) - xc[d]);
        }
        for (int d = 0; d < 3; ++d) ws[WS_XMEAN + b * 4 + d] = xm[d];
    }
}

// ---------------------------------------------------------------------------
// K1: per-node: DCT, vel angles, hh embedding, xh/vh channels.
// ---------------------------------------------------------------------------
__global__ void k_nodes(const float* __restrict__ x, const float* __restrict__ vel,
                        const float* __restrict__ h,
                        const float* __restrict__ W_emb, const float* __restrict__ b_emb,
                        const float* __restrict__ W_emb2, const float* __restrict__ b_emb2,
                        const float* __restrict__ W_coord, const float* __restrict__ W_vel,
                        float* __restrict__ ws) {
    int node = blockIdx.x * 4 + (threadIdx.x >> 6);
    int lane = threadIdx.x & 63;
    int b = node >> 8, n = node & 255;
    float xc[3], xm[3];
#pragma unroll
    for (int d = 0; d < 3; ++d) {
        xc[d] = ws[WS_XC + b * 4 + d];
        xm[d] = ws[WS_XMEAN + b * 4 + d];
    }
    const float* xp = x + node * 30;
    const float* vp = vel + node * 30;
    float xs[10][3], vl[10][3];
#pragma unroll
    for (int t = 0; t < 10; ++t)
#pragma unroll
        for (int d = 0; d < 3; ++d) {
            xs[t][d] = xp[t * 3 + d] - xc[d];
            vl[t][d] = vp[t * 3 + d];
        }
    float ang[10];
#pragma unroll
    for (int t = 0; t < 10; ++t) {
        int tp = (t == 0) ? 0 : (t - 1);
        float dot = 0.0f, n1 = 0.0f, n2 = 0.0f;
#pragma unroll
        for (int d = 0; d < 3; ++d) {
            float a = vl[tp][d], c = vl[t][d];
            dot += a * c; n1 += a * a; n2 += c * c;
        }
        float cv = dot / ((sqrtf(n1) + EPS_F) * (sqrtf(n2) + EPS_F));
        cv = fminf(1.0f, fmaxf(-1.0f, cv));
        ang[t] = acosf(cv);
    }
    float xd[10][3], vd[10][3];
    float w0 = sqrtf(0.1f), w1 = sqrtf(0.2f);
#pragma unroll
    for (int s = 0; s < 10; ++s) {
        float a0 = 0, a1 = 0, a2 = 0, c0 = 0, c1 = 0, c2 = 0;
#pragma unroll
        for (int t = 0; t < 10; ++t) {
            float coef = ((s == 0) ? w0 : w1) * cosf(PI_F * (t + 0.5f) * s * 0.1f);
            a0 += coef * xs[t][0]; a1 += coef * xs[t][1]; a2 += coef * xs[t][2];
            c0 += coef * vl[t][0]; c1 += coef * vl[t][1]; c2 += coef * vl[t][2];
        }
        xd[s][0] = a0; xd[s][1] = a1; xd[s][2] = a2;
        vd[s][0] = c0; vd[s][1] = c1; vd[s][2] = c2;
    }
    const float* hp = h + node * 10;
    float acc;
    if (lane < 32) {
        acc = b_emb[lane];
#pragma unroll
        for (int t = 0; t < 10; ++t) acc += hp[t] * W_emb[t * 32 + lane];
    } else {
        int o2 = lane - 32;
        acc = b_emb2[o2];
#pragma unroll
        for (int t = 0; t < 10; ++t) acc += ang[t] * W_emb2[t * 32 + o2];
    }
    ws[WS_HH + node * 64 + lane] = acc;
    float xh[3] = {xm[0], xm[1], xm[2]};
    float vh[3] = {0.0f, 0.0f, 0.0f};
#pragma unroll
    for (int t = 0; t < 10; ++t) {
        float wc = W_coord[t * 64 + lane];
        float wv = W_vel[t * 64 + lane];
#pragma unroll
        for (int d = 0; d < 3; ++d) {
            xh[d] += (xd[t][d] - xm[d]) * wc;
            vh[d] += vd[t][d] * wv;
        }
    }
    int cb = b * 384 * 256;
#pragma unroll
    for (int d = 0; d < 3; ++d) {
        ws[WS_XH + (node * 64 + lane) * 3 + d] = xh[d];
        ws[WS_COORDT + cb + (lane * 3 + d) * 256 + n] = xh[d];
        ws[WS_COORDT + cb + ((64 + lane) * 3 + d) * 256 + n] = vh[d];
    }
}

// ---------------------------------------------------------------------------
// K2: xm2 = mean over (n,c) of xh.
// ---------------------------------------------------------------------------
__global__ void k_xm2(float* __restrict__ ws) {
    int b = blockIdx.x, tid = threadIdx.x, lane = tid & 63, w = tid >> 6;
    const float* p = ws + WS_XH + (b * 256 + tid) * 192;
    float s0 = 0, s1 = 0, s2 = 0;
    for (int c = 0; c < 64; ++c) {
        s0 += p[c * 3 + 0]; s1 += p[c * 3 + 1]; s2 += p[c * 3 + 2];
    }
#pragma unroll
    for (int m = 1; m < 64; m <<= 1) {
        s0 += __shfl_xor(s0, m, 64);
        s1 += __shfl_xor(s1, m, 64);
        s2 += __shfl_xor(s2, m, 64);
    }
    __shared__ float sr[4][3];
    if (lane == 0) { sr[w][0] = s0; sr[w][1] = s1; sr[w][2] = s2; }
    __syncthreads();
    if (tid == 0)
        for (int d = 0; d < 3; ++d)
            ws[WS_XM2 + b * 4 + d] = (sr[0][d] + sr[1][d] + sr[2][d] + sr[3][d]) * (1.0f / 16384.0f);
}

// ---------------------------------------------------------------------------
// K3: prediction head + inverse DCT -> d_out[0 : 61440].
// ---------------------------------------------------------------------------
__global__ void k_xout(const float* __restrict__ W_pred, const float* __restrict__ ws,
                       float* __restrict__ out) {
    int nd = threadIdx.x >> 6, lane = threadIdx.x & 63;
    int node = blockIdx.x * 4 + nd;
    int b = node >> 8;
    __shared__ float sxp[4][60];
    float xm2[3];
#pragma unroll
    for (int d = 0; d < 3; ++d) xm2[d] = ws[WS_XM2 + b * 4 + d];
    if (lane < 60) {
        int o2 = lane / 3, d = lane % 3;
        const float* p = ws + WS_XH + node * 192;
        float acc = xm2[d];
        for (int c = 0; c < 64; ++c) acc += (p[c * 3 + d] - xm2[d]) * W_pred[c * 20 + o2];
        sxp[nd][lane] = acc;
    }
    __syncthreads();
    if (lane < 60) {
        int s = lane / 3, d = lane % 3;
        float w0 = sqrtf(0.05f), w1 = sqrtf(0.1f);
        float acc = ws[WS_XC + b * 4 + d];
#pragma unroll
        for (int t = 0; t < 20; ++t) {
            float coef = ((t == 0) ? w0 : w1) * cosf(PI_F * (s + 0.5f) * t * 0.05f);
            acc += coef * sxp[nd][t * 3 + d];
        }
        out[(node * 20 + s) * 3 + d] = acc;
    }
}

// ---------------------------------------------------------------------------
// K4: per-node edge-MLP rank-1 terms (bias_e, contrib_e^T).
// ---------------------------------------------------------------------------
__global__ void k_contrib1(const float* __restrict__ We1, const float* __restrict__ be1,
                           float* __restrict__ ws) {
    int node = blockIdx.x * 4 + (threadIdx.x >> 6);
    int o = threadIdx.x & 63;
    int b = node >> 8, n = node & 255;
    const float* hp = ws + WS_HH + node * 64;
    float a1 = be1[o], a2 = 0.0f;
    for (int t = 0; t < 64; ++t) {
        float hv = hp[t];
        a1 = fmaf(hv, We1[t * 64 + o], a1);
        a2 = fmaf(hv, We1[(64 + t) * 64 + o], a2);
    }
    ws[WS_BIASE + node * 64 + o] = a1;
    ws[WS_CONTRE + (b * 64 + o) * 256 + n] = a2;
}

// ---------------------------------------------------------------------------
// K6: node_new MLP + category-head rank-1 terms.
// ---------------------------------------------------------------------------
__global__ void k_nodes2(const float* __restrict__ Wn1, const float* __restrict__ bn1,
                         const float* __restrict__ Wn2, const float* __restrict__ bn2,
                         const float* __restrict__ Wk1, const float* __restrict__ bk1,
                         float* __restrict__ ws) {
    int nd = threadIdx.x >> 6;
    int o = threadIdx.x & 63;
    int node = blockIdx.x * 4 + nd;
    int b = node >> 8, n = node & 255;
    __shared__ float sg[4][64], snn[4][64];
    const float* hp = ws + WS_HH + node * 64;
    const float* ap = ws + WS_AGG + node * 64;
    float acc = bn1[o];
    for (int t = 0; t < 64; ++t) acc = fmaf(hp[t], Wn1[t * 64 + o], acc);
    for (int t = 0; t < 64; ++t) acc = fmaf(ap[t], Wn1[(64 + t) * 64 + o], acc);
    sg[nd][o] = silu(acc);
    __syncthreads();
    acc = bn2[o];
    for (int t = 0; t < 64; ++t) acc = fmaf(sg[nd][t], Wn2[t * 64 + o], acc);
    snn[nd][o] = silu(acc);
    __syncthreads();
    float bk = bk1[o], ck = 0.0f;
    for (int t = 0; t < 64; ++t) {
        float v = snn[nd][t];
        bk = fmaf(v, Wk1[t * 64 + o], bk);
        ck = fmaf(v, Wk1[(64 + t) * 64 + o], ck);
    }
    ws[WS_BIASK + node * 64 + o] = bk;
    ws[WS_CONTRK + (b * 64 + o) * 256 + n] = ck;
}

// ---------------------------------------------------------------------------
// K_pair<PASS>: MFMA pair pipeline (fp16 fragments, fp32 accumulate).
//   PASS 0 (edge):   dist -> L1(Wc1) -> L2(Wc2) -> L3(We1_cd + bias/contrib_e)
//                    -> L4(We2) -> silu -> mask -> colsum -> agg.
//   PASS 1 (categ):  same L1..L3 with Wk1_cd + bias/contrib_k
//                    -> L4(Wk2) -> silu -> softmax(4) -> out.
// Block: 512 threads = 8 waves; waves 0-3 -> i0, 4-7 -> i0+1; wave = 64 j's.
// Fragment convention: A row m = lane&15, B col n = lane&15,
// k-slot = 8*(lane>>4)+v (shared A/B convention => any HW k-permutation
// cancels). D: col = lane&15, row = 4*(lane>>4)+reg (m89-verified).
// ---------------------------------------------------------------------------
template<int PASS>
__global__ __launch_bounds__(512, 1) void k_pair(
    const float* __restrict__ Wc1, const float* __restrict__ bc1,
    const float* __restrict__ Wc2, const float* __restrict__ bc2,
    const float* __restrict__ WA, const float* __restrict__ WB,
    const float* __restrict__ bB,
    float* __restrict__ ws, float* __restrict__ out) {

    __shared__ __align__(16) _Float16 W1T[64 * 136];   // [o][c] = Wc1[c][o]
    __shared__ __align__(16) _Float16 W2T[128 * 72];   // [c][o] = Wc2[o][c]
    __shared__ __align__(16) _Float16 WAT[64 * 136];   // [o][m] = WA[128+m][o]
    __shared__ __align__(16) _Float16 WBT[64 * 72];    // [m][o] = WB[o][m]
    __shared__ __align__(16) _Float16 ACT[8][16 * 72 + 16 * 136];
    __shared__ float sci[2][384];
    __shared__ float sb1[64], sb2[128], sbB[64];
    __shared__ float sbias[2][64];
    __shared__ float sred[8][64];

    const int tid = threadIdx.x;
    const int b = blockIdx.y;
    const int i0 = blockIdx.x * 2;
    const float* cT = ws + WS_COORDT + b * 384 * 256;

    // ---- stage weights (fp16, transposed) ----
    for (int idx = tid; idx < 8192; idx += 512) {
        int c = idx >> 6, o = idx & 63;
        W1T[o * 136 + c] = (_Float16)Wc1[idx];
        WAT[o * 136 + c] = (_Float16)WA[8192 + idx];   // rows 128..255 of WA
    }
    for (int idx = tid; idx < 8192; idx += 512) {
        int o = idx >> 7, c = idx & 127;
        W2T[c * 72 + o] = (_Float16)Wc2[idx];
    }
    if (PASS == 0) {
        for (int idx = tid; idx < 4096; idx += 512) {
            int o = idx >> 6, m = idx & 63;
            WBT[m * 72 + o] = (_Float16)WB[idx];
        }
    } else {
        for (int idx = tid; idx < 4608; idx += 512) WBT[idx] = (_Float16)0.0f;
        __syncthreads();
        if (tid < 256) {
            int o = tid >> 2, cat = tid & 3;
            WBT[cat * 72 + o] = (_Float16)WB[tid];
        }
    }
    for (int idx = tid; idx < 768; idx += 512) {
        int ii = idx / 384, c3 = idx % 384;
        sci[ii][c3] = cT[c3 * 256 + (i0 + ii)];
    }
    if (tid < 64)  sb1[tid] = bc1[tid];
    if (tid < 128) sb2[tid] = bc2[tid];
    if (tid < 64)  sbB[tid] = (PASS == 0) ? bB[tid] : (tid < 4 ? bB[tid] : 0.0f);
    {
        const float* bias = ws + ((PASS == 0) ? WS_BIASE : WS_BIASK);
        if (tid < 128) {
            int ii = tid >> 6, o = tid & 63;
            sbias[ii][o] = bias[(b * 256 + i0 + ii) * 64 + o];
        }
    }
    __syncthreads();

    const int w = tid >> 6, lane = tid & 63;
    const int lr = lane & 15, lg = lane >> 4;
    const int ii = w >> 2, jw = w & 3;
    const int i = i0 + ii;
    const float* scii = sci[ii];
    const float* contrib = ws + ((PASS == 0) ? WS_CONTRE : WS_CONTRK) + b * 64 * 256;
    _Float16* t1s = ACT[w];              // [16][72]  (t1, then e1)
    _Float16* cds = ACT[w] + 16 * 72;    // [16][136]

    float pacc[4] = {0.0f, 0.0f, 0.0f, 0.0f};

    for (int mt = 0; mt < 4; ++mt) {
        const int jbase = 64 * jw + 16 * mt;
        const int j = jbase + lr;

        // ---- dist A-fragments (fp32 math, fp16 cast) ----
        f16x8 as[4];
#pragma unroll
        for (int kt = 0; kt < 4; ++kt) {
            union { f16x8 v; _Float16 s[8]; } u;
#pragma unroll
            for (int v = 0; v < 8; ++v) {
                int c = 32 * kt + 8 * lg + v;
                float dx = scii[c * 3 + 0] - cT[(c * 3 + 0) * 256 + j];
                float dy = scii[c * 3 + 1] - cT[(c * 3 + 1) * 256 + j];
                float dz = scii[c * 3 + 2] - cT[(c * 3 + 2) * 256 + j];
                u.s[v] = (_Float16)sqrtf(dx * dx + dy * dy + dz * dz);
            }
            as[kt] = u.v;
        }

        // ---- L1: t1 = silu(dist @ Wc1 + bc1), N=64, K=128 ----
#pragma unroll
        for (int nt = 0; nt < 4; ++nt) {
            int o = 16 * nt + lr;
            float bv = sb1[o];
            f32x4 d = {bv, bv, bv, bv};
#pragma unroll
            for (int kt = 0; kt < 4; ++kt) {
                f16x8 bf = *(const f16x8*)&W1T[o * 136 + 32 * kt + 8 * lg];
                d = __builtin_amdgcn_mfma_f32_16x16x32_f16(as[kt], bf, d, 0, 0, 0);
            }
#pragma unroll
            for (int r = 0; r < 4; ++r)
                t1s[(4 * lg + r) * 72 + o] = (_Float16)silu(d[r]);
        }
        asm volatile("s_waitcnt lgkmcnt(0)" ::: "memory");

        // ---- L2: cd = silu(t1 @ Wc2 + bc2), N=128, K=64 ----
        f16x8 a2[2];
#pragma unroll
        for (int kt = 0; kt < 2; ++kt)
            a2[kt] = *(const f16x8*)&t1s[lr * 72 + 32 * kt + 8 * lg];
#pragma unroll
        for (int ntc = 0; ntc < 8; ++ntc) {
            int cc = 16 * ntc + lr;
            float bv = sb2[cc];
            f32x4 d = {bv, bv, bv, bv};
#pragma unroll
            for (int kt = 0; kt < 2; ++kt) {
                f16x8 bf = *(const f16x8*)&W2T[cc * 72 + 32 * kt + 8 * lg];
                d = __builtin_amdgcn_mfma_f32_16x16x32_f16(a2[kt], bf, d, 0, 0, 0);
            }
#pragma unroll
            for (int r = 0; r < 4; ++r)
                cds[(4 * lg + r) * 136 + cc] = (_Float16)silu(d[r]);
        }
        asm volatile("s_waitcnt lgkmcnt(0)" ::: "memory");

        // ---- L3: e1/l1 = silu(bias + contrib + cd @ WA_cd), N=64, K=128 ----
        f16x8 a3[4];
#pragma unroll
        for (int kt = 0; kt < 4; ++kt)
            a3[kt] = *(const f16x8*)&cds[lr * 136 + 32 * kt + 8 * lg];
#pragma unroll
        for (int nt = 0; nt < 4; ++nt) {
            int o = 16 * nt + lr;
            float4 ce = *(const float4*)&contrib[o * 256 + jbase + 4 * lg];
            float bv = sbias[ii][o];
            f32x4 d = {bv + ce.x, bv + ce.y, bv + ce.z, bv + ce.w};
#pragma unroll
            for (int kt = 0; kt < 4; ++kt) {
                f16x8 bf = *(const f16x8*)&WAT[o * 136 + 32 * kt + 8 * lg];
                d = __builtin_amdgcn_mfma_f32_16x16x32_f16(a3[kt], bf, d, 0, 0, 0);
            }
#pragma unroll
            for (int r = 0; r < 4; ++r)
                t1s[(4 * lg + r) * 72 + o] = (_Float16)silu(d[r]);
        }
        asm volatile("s_waitcnt lgkmcnt(0)" ::: "memory");

        // ---- L4 ----
        f16x8 a4[2];
#pragma unroll
        for (int kt = 0; kt < 2; ++kt)
            a4[kt] = *(const f16x8*)&t1s[lr * 72 + 32 * kt + 8 * lg];

        if (PASS == 0) {
            // edge = silu(e1 @ We2 + be2); mask j==i; column-sum accumulate
#pragma unroll
            for (int nt = 0; nt < 4; ++nt) {
                int o = 16 * nt + lr;
                float bv = sbB[o];
                f32x4 d = {bv, bv, bv, bv};
#pragma unroll
                for (int kt = 0; kt < 2; ++kt) {
                    f16x8 bf = *(const f16x8*)&WBT[o * 72 + 32 * kt + 8 * lg];
                    d = __builtin_amdgcn_mfma_f32_16x16x32_f16(a4[kt], bf, d, 0, 0, 0);
                }
#pragma unroll
                for (int r = 0; r < 4; ++r) {
                    int jj = jbase + 4 * lg + r;
                    float e = silu(d[r]);
                    pacc[nt] += (jj == i) ? 0.0f : e;
                }
            }
        } else {
            // logits = silu(l1 @ Wk2 + bk2); softmax over 4 cats (lanes lr 0..3)
            float bv = sbB[lr];
            f32x4 d = {bv, bv, bv, bv};
#pragma unroll
            for (int kt = 0; kt < 2; ++kt) {
                f16x8 bf = *(const f16x8*)&WBT[lr * 72 + 32 * kt + 8 * lg];
                d = __builtin_amdgcn_mfma_f32_16x16x32_f16(a4[kt], bf, d, 0, 0, 0);
            }
#pragma unroll
            for (int r = 0; r < 4; ++r) {
                float lgv = silu(d[r]);
                float mx = fmaxf(lgv, __shfl_xor(lgv, 1, 64));
                mx = fmaxf(mx, __shfl_xor(mx, 2, 64));
                float e = __expf(lgv - mx);
                float s = e + __shfl_xor(e, 1, 64);
                s = s + __shfl_xor(s, 2, 64);
                float prob = e * __builtin_amdgcn_rcpf(s);
                if (lr < 4) {
                    int jj = jbase + 4 * lg + r;
                    out[61440 + ((b * 256 + i) * 256 + jj) * 4 + lr] = prob;
                }
            }
        }
    }

    if (PASS == 0) {
#pragma unroll
        for (int nt = 0; nt < 4; ++nt) {
            pacc[nt] += __shfl_xor(pacc[nt], 16, 64);
            pacc[nt] += __shfl_xor(pacc[nt], 32, 64);
            if (lg == 0) sred[w][16 * nt + lr] = pacc[nt];
        }
        __syncthreads();
        if (tid < 128) {
            int iw = tid >> 6, o = tid & 63;
            float s = sred[iw * 4 + 0][o] + sred[iw * 4 + 1][o] +
                      sred[iw * 4 + 2][o] + sred[iw * 4 + 3][o];
            ws[WS_AGG + (b * 256 + i0 + iw) * 64 + o] = s;
        }
    }
}

// ---------------------------------------------------------------------------
extern "C" void kernel_launch(void* const* d_in, const int* in_sizes, int n_in,
                              void* d_out, int out_size, void* d_ws, size_t ws_size,
                              hipStream_t stream) {
    (void)in_sizes; (void)n_in; (void)out_size; (void)ws_size;
    const float* h      = (const float*)d_in[0];
    const float* x      = (const float*)d_in[1];
    const float* vel    = (const float*)d_in[2];
    const float* W_emb  = (const float*)d_in[3];
    const float* b_emb  = (const float*)d_in[4];
    const float* W_emb2 = (const float*)d_in[5];
    const float* b_emb2 = (const float*)d_in[6];
    const float* W_coord= (const float*)d_in[7];
    const float* W_vel  = (const float*)d_in[8];
    const float* W_pred = (const float*)d_in[9];
    const float* Wc1    = (const float*)d_in[10];
    const float* bc1    = (const float*)d_in[11];
    const float* Wc2    = (const float*)d_in[12];
    const float* bc2    = (const float*)d_in[13];
    const float* We1    = (const float*)d_in[14];
    const float* be1    = (const float*)d_in[15];
    const float* We2    = (const float*)d_in[16];
    const float* be2    = (const float*)d_in[17];
    const float* Wn1    = (const float*)d_in[18];
    const float* bn1    = (const float*)d_in[19];
    const float* Wn2    = (const float*)d_in[20];
    const float* bn2    = (const float*)d_in[21];
    const float* Wk1    = (const float*)d_in[22];
    const float* bk1    = (const float*)d_in[23];
    const float* Wk2    = (const float*)d_in[24];
    const float* bk2    = (const float*)d_in[25];
    float* ws  = (float*)d_ws;
    float* out = (float*)d_out;

    k_stats<<<4, 256, 0, stream>>>(x, ws);
    k_nodes<<<256, 256, 0, stream>>>(x, vel, h, W_emb, b_emb, W_emb2, b_emb2,
                                     W_coord, W_vel, ws);
    k_xm2<<<4, 256, 0, stream>>>(ws);
    k_xout<<<256, 256, 0, stream>>>(W_pred, ws, out);
    k_contrib1<<<256, 256, 0, stream>>>(We1, be1, ws);
    k_pair<0><<<dim3(128, 4), 512, 0, stream>>>(Wc1, bc1, Wc2, bc2, We1, We2, be2, ws, out);
    k_nodes2<<<256, 256, 0, stream>>>(Wn1, bn1, Wn2, bn2, Wk1, bk1, ws);
    k_pair<1><<<dim3(128, 4), 512, 0, stream>>>(Wc1, bc1, Wc2, bc2, Wk1, Wk2, bk2, ws, out);
}